// Round 4
// baseline (9767.691 us; speedup 1.0000x reference)
//
#include <hip/hip_runtime.h>
#include <cstddef>

#define BB 64
#define LL 512
#define II 256
#define HH 512

typedef _Float16 f16;
typedef _Float16 f16x8 __attribute__((ext_vector_type(8)));
typedef float f32x4 __attribute__((ext_vector_type(4)));

// ws layout in f16 units:
//   W0F  @ 0        : [j=16][kb=16][tn=2][L=64][e=8]  = 262144  (512KB)
//   W1F  @ 262144   : same                             = 262144
//   WGF  @ 524288   : [j=16][kb=24][tt=6][L=64][e=8]  = 1179648 (2.25MB)
//   YBUF @ 1703936  : [c=4][p=2][m=16][col=512]        = 65536
// byte offsets:
//   FLAGS @ 3538944 : 4 clusters x 256B = 16 slots x 16B each.
//     slot j byte 0 : barrier flag (uint)      — ONLY ever sc0 sc1
//     slot j byte 4 : per-block fail word      — ONLY ever sc0 sc1
// Probe tokens: ybuf half-1, row 0, col j*32 — block (c,j)'s own 64B line,
// never read before round q=0 and fully overwritten during q=0 by block
// (c,j) itself (so a dirty L2 token line can never clobber fresh data).
// Footprint ends at FLAGS_B + 1024 — byte-identical to the proven baseline.
#define W0F_H 0
#define W1F_H 262144
#define WGF_H 524288
#define YBUF_H 1703936
#define FLAGS_B 3538944
#define N0 262144
#define N1 262144
#define N2 1179648
#define N3 32768
#define N4 256
#define PREP_TOTAL (N0 + N1 + N2 + N3 + N4)

__global__ void prep_kernel(const float* __restrict__ dw0, const float* __restrict__ dw1,
                            const float* __restrict__ w_ih, const float* __restrict__ w_hh,
                            const float* __restrict__ h0, f16* __restrict__ wsh) {
    int idx = blockIdx.x * 256 + threadIdx.x;
    if (idx >= PREP_TOTAL) return;
    if (idx < N0 + N1) {
        const float* src = (idx < N0) ? dw0 : dw1;
        int r = (idx < N0) ? idx : idx - N0;
        int e = r & 7, L = (r >> 3) & 63, tn = (r >> 9) & 1, kb = (r >> 10) & 15, j = r >> 14;
        int n = j * 32 + tn * 16 + (L & 15);
        int k = kb * 32 + (L >> 4) * 8 + e;
        wsh[idx] = (f16)src[n * 512 + k];
        return;
    }
    idx -= (N0 + N1);
    if (idx < N2) {
        int e = idx & 7, L = (idx >> 3) & 63;
        int rest = idx >> 9;
        int tt = rest % 6, r2 = rest / 6;
        int kb = r2 % 24, j = r2 / 24;
        int g = tt >> 1, tn = tt & 1;
        int n = g * 512 + j * 32 + tn * 16 + (L & 15);
        int kc = kb * 32 + (L >> 4) * 8 + e;
        float v = (kc < 256) ? w_ih[n * 256 + kc] : w_hh[n * 512 + (kc - 256)];
        wsh[WGF_H + idx] = (f16)v;
        return;
    }
    idx -= N2;
    if (idx < N3) {
        int col = idx & 511, m = (idx >> 9) & 15, c = idx >> 13;
        wsh[YBUF_H + (size_t)c * 16384 + m * 512 + col] = (f16)h0[col];
        return;
    }
    idx -= N3;
    ((unsigned*)((char*)wsh + FLAGS_B))[idx] = 0u;  // zero 4x64 flag uints (flags + fail words)
}

// Scoped coherent ops. SYS=1: sc0 sc1 (device scope at L3) — the proven
// baseline path, correct for any placement. SYS=0: sc0 only — intended
// XCD-local L2 scope. SYS=0 is used ONLY for non-looping DATA ops (ybuf
// store / stage load), and only after the runtime probe below verified the
// exact store->repeated-load visibility pattern the data path relies on.
// ALL spin loops in this kernel are sc0 sc1 (hang-impossible by design).
template<int SYS>
__device__ __forceinline__ void st_u32_sc(unsigned* p, unsigned v) {
    if constexpr (SYS)
        asm volatile("global_store_dword %0, %1, off sc0 sc1" :: "v"(p), "v"(v) : "memory");
    else
        asm volatile("global_store_dword %0, %1, off sc0" :: "v"(p), "v"(v) : "memory");
}
template<int SYS>
__device__ __forceinline__ unsigned ld_u32_sc(const unsigned* p) {
    unsigned v;
    if constexpr (SYS)
        asm volatile("global_load_dword %0, %1, off sc0 sc1\n\ts_waitcnt vmcnt(0)"
                     : "=v"(v) : "v"(p) : "memory");
    else
        asm volatile("global_load_dword %0, %1, off sc0\n\ts_waitcnt vmcnt(0)"
                     : "=v"(v) : "v"(p) : "memory");
    return v;
}
template<int SYS>
__device__ __forceinline__ void st_f16_sc(f16* p, f16 v) {
    unsigned u = (unsigned)__builtin_bit_cast(unsigned short, v);
    if constexpr (SYS)
        asm volatile("global_store_short %0, %1, off sc0 sc1" :: "v"(p), "v"(u) : "memory");
    else
        asm volatile("global_store_short %0, %1, off sc0" :: "v"(p), "v"(u) : "memory");
}

// Drain this wave's vmem ops (covers inline-asm stores), barrier, post our
// slot, poll all 16 slots (16B stride). ALWAYS device scope — byte-for-byte
// the machinery proven over 4608 rounds/run in the 9148us baseline.
__device__ __forceinline__ void cluster_sync(unsigned* slots, int j, unsigned target, int tid) {
    asm volatile("s_waitcnt vmcnt(0)" ::: "memory");
    __syncthreads();
    if (tid == 0) st_u32_sc<1>(slots + j * 4, target);
    if (tid < 16) {
        while (ld_u32_sc<1>(slots + tid * 4) < target) __builtin_amdgcn_s_sleep(1);
    }
    __syncthreads();
}

// stage 16x512 f16 activations from the cluster ping-pong buffer
template<int SYS>
__device__ __forceinline__ void stageA_sc(const f16* __restrict__ rbuf, f16* __restrict__ A,
                                          int tid) {
    int m = tid >> 5, o = tid & 31;
    const f16* p = &rbuf[m * 512 + o * 16];
    f32x4 v0, v1;
    if constexpr (SYS)
        asm volatile("global_load_dwordx4 %0, %2, off sc0 sc1\n\t"
                     "global_load_dwordx4 %1, %2, off offset:16 sc0 sc1\n\t"
                     "s_waitcnt vmcnt(0)"
                     : "=&v"(v0), "=&v"(v1) : "v"(p) : "memory");
    else
        asm volatile("global_load_dwordx4 %0, %2, off sc0\n\t"
                     "global_load_dwordx4 %1, %2, off offset:16 sc0\n\t"
                     "s_waitcnt vmcnt(0)"
                     : "=&v"(v0), "=&v"(v1) : "v"(p) : "memory");
    *(f32x4*)&A[m * 520 + o * 16] = v0;
    *(f32x4*)&A[m * 520 + o * 16 + 8] = v1;
}

// ODE matvec: this wave's partial C for tile tn=w&1 over kb in [kh*4, kh*4+4)
__device__ __forceinline__ f32x4 ode_mm(const f16* __restrict__ Ws, const f16* __restrict__ A,
                                        int w, int L) {
    const int tn = w & 1, kh = w >> 1;
    const int L15 = L & 15, Lq = L >> 4;
    f32x4 acc = {0.f, 0.f, 0.f, 0.f};
#pragma unroll
    for (int i = 0; i < 4; ++i) {
        int kb = kh * 4 + i;
        f16x8 a = *(const f16x8*)&A[L15 * 520 + kb * 32 + Lq * 8];
        f16x8 b = *(const f16x8*)&Ws[(kb * 2 + tn) * 512 + L * 8];
        acc = __builtin_amdgcn_mfma_f32_16x16x32_f16(a, b, acc, 0, 0, 0);
    }
    return acc;
}

template<int SYS>
__device__ __forceinline__ void run_loop(
    const float* __restrict__ x, const float* __restrict__ tds,
    const float* __restrict__ b_ih, const float* __restrict__ b_hh,
    const float* __restrict__ db0, const float* __restrict__ db1,
    const float* __restrict__ h0, const int* __restrict__ seq_lens,
    f16* __restrict__ wsh, float* __restrict__ out, int c, int j,
    f16* W0s, f16* W1s, f16* Abuf, f16* Xbuf,
    float* Red, float* Gate, float* tdS, int* slS) {
    const int tid = threadIdx.x;
    const int w = tid >> 6;
    const int L = tid & 63;
    const int L15 = L & 15;
    const int Lq = L >> 4;
    const int b0 = c * 16;

    unsigned* slots = (unsigned*)((char*)wsh + FLAGS_B + (size_t)c * 256);
    f16* yb0 = wsh + YBUF_H + (size_t)c * 16384;

    {
        const f16* w0g = wsh + W0F_H + (size_t)j * 16384;
        const f16* w1g = wsh + W1F_H + (size_t)j * 16384;
        for (int i = tid; i < 2048; i += 512) {
            *(f16x8*)&W0s[i * 8] = *(const f16x8*)&w0g[i * 8];
            *(f16x8*)&W1s[i * 8] = *(const f16x8*)&w1g[i * 8];
        }
    }
    f16x8 wgr[24];
    if (w < 6) {
        const f16* wgg = wsh + WGF_H;
#pragma unroll
        for (int kb = 0; kb < 24; ++kb)
            wgr[kb] = *(const f16x8*)&wgg[((((size_t)j * 24 + kb) * 6 + w) * 64 + L) * 8];
    }
    float h[4], k1[4], k2[4], k3[4], hode[4];
    float d0b = 0.f, d1b = 0.f, bir = 0.f, bhr = 0.f, biz = 0.f, bhz = 0.f, bin_ = 0.f, bhn = 0.f;
    int col = j * 32 + (w & 1) * 16 + L15;
    if (w < 2) {
        float hv = h0[col];
#pragma unroll
        for (int r = 0; r < 4; ++r) h[r] = hv;
        d0b = db0[col]; d1b = db1[col];
        bir = b_ih[col];        bhr = b_hh[col];
        biz = b_ih[512 + col];  bhz = b_hh[512 + col];
        bin_ = b_ih[1024 + col]; bhn = b_hh[1024 + col];
    }
    if (tid < 16) slS[tid] = seq_lens[b0 + tid];
    __syncthreads();

    // Main loop. Barrier targets are q+5 (targets 1..4 were consumed by the
    // coherence-probe rounds); buffer parity still keyed on q itself.
    for (int t = 0; t < LL; ++t) {
        const int qb = t * 9;
        {
            int m = tid >> 5, o = tid & 31;
            bool valid = t < slS[m];
            const float* xp = x + ((size_t)(b0 + m) * LL + t) * II + o * 8;
            f16x8 xv;
            if (valid) {
                f32x4 xa = *(const f32x4*)xp;
                f32x4 xb = *(const f32x4*)(xp + 4);
#pragma unroll
                for (int e = 0; e < 4; ++e) { xv[e] = (f16)xa[e]; xv[4 + e] = (f16)xb[e]; }
            } else {
#pragma unroll
                for (int e = 0; e < 8; ++e) xv[e] = (f16)0.f;
            }
            *(f16x8*)&Xbuf[m * 264 + o * 8] = xv;
            if (tid < 16) tdS[tid] = (t < slS[tid]) ? tds[(size_t)(b0 + tid) * LL + t] : 0.f;
        }
        __syncthreads();

#pragma unroll 1
        for (int s = 0; s < 4; ++s) {
            {
                const int q = qb + 2 * s;
                const f16* rbuf = yb0 + (q & 1) * 8192;
                f16* wbuf = yb0 + ((q & 1) ^ 1) * 8192;
                stageA_sc<SYS>(rbuf, Abuf, tid);
                __syncthreads();
                f32x4 acc = ode_mm(W0s, Abuf, w, L);
                if (w >= 2) {
#pragma unroll
                    for (int r = 0; r < 4; ++r)
                        Red[(((w >> 1) - 1) * 2 + (w & 1)) * 256 + L * 4 + r] = acc[r];
                }
                __syncthreads();
                if (w < 2) {
#pragma unroll
                    for (int p = 0; p < 3; ++p)
#pragma unroll
                        for (int r = 0; r < 4; ++r) acc[r] += Red[(p * 2 + w) * 256 + L * 4 + r];
#pragma unroll
                    for (int r = 0; r < 4; ++r) {
                        float u = tanhf(acc[r] + d0b);
                        st_f16_sc<SYS>(&wbuf[(Lq * 4 + r) * 512 + col], (f16)u);
                    }
                }
                cluster_sync(slots, j, (unsigned)(q + 5), tid);
            }
            {
                const int q = qb + 2 * s + 1;
                const f16* rbuf = yb0 + (q & 1) * 8192;
                f16* wbuf = yb0 + ((q & 1) ^ 1) * 8192;
                stageA_sc<SYS>(rbuf, Abuf, tid);
                __syncthreads();
                f32x4 acc = ode_mm(W1s, Abuf, w, L);
                if (w >= 2) {
#pragma unroll
                    for (int r = 0; r < 4; ++r)
                        Red[(((w >> 1) - 1) * 2 + (w & 1)) * 256 + L * 4 + r] = acc[r];
                }
                __syncthreads();
                if (w < 2) {
#pragma unroll
                    for (int p = 0; p < 3; ++p)
#pragma unroll
                        for (int r = 0; r < 4; ++r) acc[r] += Red[(p * 2 + w) * 256 + L * 4 + r];
#pragma unroll
                    for (int r = 0; r < 4; ++r) {
                        float kv = tanhf(acc[r] + d1b) * tdS[Lq * 4 + r];
                        float yv;
                        if (s == 0)      { k1[r] = kv; yv = h[r] + kv * (1.f / 3.f); }
                        else if (s == 1) { k2[r] = kv; yv = h[r] + kv - k1[r] * (1.f / 3.f); }
                        else if (s == 2) { k3[r] = kv; yv = h[r] + k1[r] - k2[r] + kv; }
                        else { hode[r] = h[r] + (k1[r] + 3.f * (k2[r] + k3[r]) + kv) * 0.125f;
                               yv = hode[r]; }
                        st_f16_sc<SYS>(&wbuf[(Lq * 4 + r) * 512 + col], (f16)yv);
                    }
                }
                cluster_sync(slots, j, (unsigned)(q + 5), tid);
            }
        }

        {
            const int q = qb + 8;
            const f16* rbuf = yb0 + (q & 1) * 8192;
            f16* wbuf = yb0 + ((q & 1) ^ 1) * 8192;
            stageA_sc<SYS>(rbuf, Abuf, tid);
            __syncthreads();
            f32x4 aA = {0.f, 0.f, 0.f, 0.f};
            f32x4 aB = {0.f, 0.f, 0.f, 0.f};
            if (w < 6) {
#pragma unroll
                for (int kb = 0; kb < 8; ++kb) {
                    f16x8 a = *(const f16x8*)&Xbuf[L15 * 264 + kb * 32 + Lq * 8];
                    aA = __builtin_amdgcn_mfma_f32_16x16x32_f16(a, wgr[kb], aA, 0, 0, 0);
                }
#pragma unroll
                for (int kb = 8; kb < 24; ++kb) {
                    f16x8 a = *(const f16x8*)&Abuf[L15 * 520 + (kb - 8) * 32 + Lq * 8];
                    aB = __builtin_amdgcn_mfma_f32_16x16x32_f16(a, wgr[kb], aB, 0, 0, 0);
                }
            }
            if (w < 4) {
#pragma unroll
                for (int r = 0; r < 4; ++r) Gate[w * 256 + L * 4 + r] = aA[r] + aB[r];
            } else if (w < 6) {
#pragma unroll
                for (int r = 0; r < 4; ++r) {
                    Gate[w * 256 + L * 4 + r] = aA[r];
                    Gate[(w + 2) * 256 + L * 4 + r] = aB[r];
                }
            }
            __syncthreads();
            if (w < 2) {
#pragma unroll
                for (int r = 0; r < 4; ++r) {
                    float g0  = Gate[(0 + w) * 256 + L * 4 + r];
                    float g1  = Gate[(2 + w) * 256 + L * 4 + r];
                    float gix = Gate[(4 + w) * 256 + L * 4 + r];
                    float ghn = Gate[(6 + w) * 256 + L * 4 + r];
                    float rg = 1.f / (1.f + __expf(-(g0 + bir + bhr)));
                    float z  = 1.f / (1.f + __expf(-(g1 + biz + bhz)));
                    float nn = tanhf(gix + bin_ + rg * (ghn + bhn));
                    float hn = (1.f - z) * nn + z * hode[r];
                    h[r] = hn;
                    int m = Lq * 4 + r;
                    out[((size_t)(b0 + m) * LL + t) * HH + col] = hn;
                    st_f16_sc<SYS>(&wbuf[m * 512 + col], (f16)hn);
                }
            }
            cluster_sync(slots, j, (unsigned)(q + 5), tid);
        }
    }
}

__launch_bounds__(512, 1)
__global__ void odegru_kernel(const float* __restrict__ x, const float* __restrict__ tds,
                              const float* __restrict__ b_ih, const float* __restrict__ b_hh,
                              const float* __restrict__ db0, const float* __restrict__ db1,
                              const float* __restrict__ h0, const int* __restrict__ seq_lens,
                              f16* __restrict__ wsh, float* __restrict__ out) {
    __shared__ f16 W0s[16384];
    __shared__ f16 W1s[16384];
    __shared__ f16 Abuf[16 * 520];
    __shared__ f16 Xbuf[16 * 264];
    __shared__ float Red[3 * 2 * 64 * 4];
    __shared__ float Gate[8 * 64 * 4];
    __shared__ float tdS[16];
    __shared__ int slS[16];
    __shared__ int scopeS;

    const int tid = threadIdx.x;
    const int bid = blockIdx.x;
    // Static assignment: 128 blocks; residue-8 grouping so that under the
    // (empirical, perf-only) round-robin block->XCD dispatch, all 16 members
    // of a cluster share one XCD. Clusters 4..7 are spares that exit at once.
    // If placement differs, the probe below fails closed into the proven
    // device-scope (sc0 sc1) data path.
    const int c = bid & 7;
    const int j = bid >> 3;
    if (c >= 4) return;

    unsigned* slots = (unsigned*)((char*)wsh + FLAGS_B + (size_t)c * 256);
    f16* yb0 = wsh + YBUF_H + (size_t)c * 16384;
    // Probe token for block (c,jj): ybuf half-1 row 0 col jj*32 (own 64B line)
    unsigned* tok0 = (unsigned*)(yb0 + 8192);

    // ---- one-time L2-coherence probe; every spin is sc0 sc1 (proven) ----
    unsigned long long mA = 0ull, mB = 0ull;
    // Phase A: post token P1 with an sc0-only store.
    if (tid == 0) st_u32_sc<0>(tok0 + j * 16, 0xA5A50000u | (unsigned)j);
    cluster_sync(slots, j, 1u, tid);
    // Phase B: read all 16 tokens once (sc0). Fills reader caches.
    if (tid < 16) {
        unsigned v = ld_u32_sc<0>(tok0 + tid * 16);
        mA = __ballot(v != (0xA5A50000u | (unsigned)tid));
    }
    cluster_sync(slots, j, 2u, tid);
    // Phase C: owner REWRITES its token to P2 (sc0).
    if (tid == 0) st_u32_sc<0>(tok0 + j * 16, 0x5A5A0000u | (unsigned)j);
    cluster_sync(slots, j, 3u, tid);
    // Phase D: RE-READ the same addresses (sc0). A cross-XCD or L1-stale
    // reader still sees P1 -> fail. This is exactly the repeated-read
    // pattern the SYS=0 data path relies on.
    if (tid < 16) {
        unsigned v = ld_u32_sc<0>(tok0 + tid * 16);
        mB = __ballot(v != (0x5A5A0000u | (unsigned)tid));
    }
    // Publish this block's fail word (sys scope, flag-slot padding), then a
    // sys barrier makes all 16 fail words visible to everyone.
    if (tid == 0) st_u32_sc<1>(slots + j * 4 + 1, (unsigned)((mA | mB) & 0xFFFFull));
    cluster_sync(slots, j, 4u, tid);
    if (tid < 16) {
        unsigned fw = ld_u32_sc<1>(slots + tid * 4 + 1);
        unsigned long long anyfail = __ballot(fw != 0u);
        if (tid == 0) scopeS = (anyfail == 0ull) ? 0 : 1;
    }
    __syncthreads();

    if (scopeS == 0)
        run_loop<0>(x, tds, b_ih, b_hh, db0, db1, h0, seq_lens, wsh, out, c, j,
                    W0s, W1s, Abuf, Xbuf, Red, Gate, tdS, slS);
    else
        run_loop<1>(x, tds, b_ih, b_hh, db0, db1, h0, seq_lens, wsh, out, c, j,
                    W0s, W1s, Abuf, Xbuf, Red, Gate, tdS, slS);
}

__global__ void finalize_kernel(const int* __restrict__ seq_lens, float* __restrict__ out) {
    int b = blockIdx.x;
    int n = threadIdx.x;
    int sl = seq_lens[b];
    out[(size_t)BB * LL * HH + (size_t)b * HH + n] =
        out[((size_t)b * LL + (sl - 1)) * HH + n];
}

extern "C" void kernel_launch(void* const* d_in, const int* in_sizes, int n_in,
                              void* d_out, int out_size, void* d_ws, size_t ws_size,
                              hipStream_t stream) {
    const float* x    = (const float*)d_in[0];
    const float* tds  = (const float*)d_in[1];
    const float* w_ih = (const float*)d_in[2];
    const float* w_hh = (const float*)d_in[3];
    const float* b_ih = (const float*)d_in[4];
    const float* b_hh = (const float*)d_in[5];
    const float* dw0  = (const float*)d_in[6];
    const float* db0  = (const float*)d_in[7];
    const float* dw1  = (const float*)d_in[8];
    const float* db1  = (const float*)d_in[9];
    const float* h0   = (const float*)d_in[10];
    const int* seq_lens = (const int*)d_in[11];
    float* out = (float*)d_out;
    f16* wsh = (f16*)d_ws;

    prep_kernel<<<(PREP_TOTAL + 255) / 256, 256, 0, stream>>>(dw0, dw1, w_ih, w_hh, h0, wsh);
    odegru_kernel<<<128, 512, 0, stream>>>(x, tds, b_ih, b_hh, db0, db1, h0, seq_lens, wsh, out);
    finalize_kernel<<<BB, HH, 0, stream>>>(seq_lens, out);
}